// Round 4
// baseline (105.569 us; speedup 1.0000x reference)
//
#include <hip/hip_runtime.h>
#include <hip/hip_bf16.h>
#include <cmath>

#define T_STEPS 128
#define BATCH   64
#define NI      784
#define NIP     800      // padded K (25 * 32)
#define NH      512
#define NO      10
#define M1      (T_STEPS*BATCH)       // 8192
#define NT_H    (BATCH*NH)            // 32768
#define NT_O    (BATCH*NO)            // 640
#define OUT_HALF (T_STEPS*BATCH*NO)   // 81920
#define TB      16                    // time-tile for the scan

typedef __attribute__((ext_vector_type(8))) short short8;
typedef __attribute__((ext_vector_type(4))) float f32x4;
typedef __attribute__((ext_vector_type(8))) unsigned short u16x8;

static __device__ __forceinline__ unsigned short f2b_bits(float x) {
    __hip_bfloat16 h = __float2bfloat16(x);
    return *reinterpret_cast<unsigned short*>(&h);
}
static __device__ __forceinline__ float b2f_bits(unsigned short u) {
    union { unsigned int i; float f; } v; v.i = ((unsigned int)u) << 16; return v.f;
}

// --- c table: c[j] = (j+1)^0.8 - j^0.8 --------------------------------------
__global__ void init_c_kernel(float* __restrict__ c) {
    int j = threadIdx.x;
    if (j < 192) {
        double a = pow((double)(j + 1), 0.8);
        double b = pow((double)j, 0.8);
        c[j] = (float)(a - b);
    }
}

// --- cast + pad f32 -> bf16, optional (b,t)->(t,b) row permute --------------
// dst [rows][800]; mode0: src [rows][784]; mode1: src data[b][t][784], dst row r=t*64+b
__global__ __launch_bounds__(256) void cast_pad_kernel(const float* __restrict__ src,
                                                       __hip_bfloat16* __restrict__ dst,
                                                       int rows, int mode) {
    int idx = blockIdx.x * 256 + threadIdx.x;
    if (idx >= rows * 200) return;
    int r  = idx / 200;
    int n4 = (idx - r * 200) * 4;
    int srow = r;
    if (mode == 1) { int t = r >> 6, b = r & 63; srow = b * T_STEPS + t; }
    ushort4 o;
    if (n4 < NI) {
        const float4 f = *reinterpret_cast<const float4*>(src + (size_t)srow * NI + n4);
        o.x = f2b_bits(f.x); o.y = f2b_bits(f.y); o.z = f2b_bits(f.z); o.w = f2b_bits(f.w);
    } else {
        o.x = o.y = o.z = o.w = 0;
    }
    *reinterpret_cast<ushort4*>(dst + (size_t)r * NIP + n4) = o;
}

// --- bf16 MFMA GEMM: C[M][N] = A[M][Kp] * B[N][Kp]^T  (both row-major) ------
// tile 128x128, 4 waves (2x2), each wave 64x64 = 4x4 frags of 16x16x32
__global__ __launch_bounds__(256) void gemm_bf16_kernel(const __hip_bfloat16* __restrict__ A,
                                                        const __hip_bfloat16* __restrict__ B,
                                                        __hip_bfloat16* __restrict__ C,
                                                        int N, int Kp) {
    __shared__ __hip_bfloat16 As[128 * 32];
    __shared__ __hip_bfloat16 Bs[128 * 32];
    const int tid  = threadIdx.x;
    const int wave = tid >> 6, lane = tid & 63;
    const int wm = wave >> 1, wn = wave & 1;
    const int bm = blockIdx.x, bn = blockIdx.y;
    const int lrow = lane >> 2;      // 0..15
    const int lchk = lane & 3;       // 0..3

    f32x4 acc[4][4] = {};

    for (int k0 = 0; k0 < Kp; k0 += 32) {
#pragma unroll
        for (int p = 0; p < 2; ++p) {
            const int rbase = p * 64 + wave * 16;
            {
                const __hip_bfloat16* g = A + (size_t)(bm * 128 + rbase + lrow) * Kp + k0 + lchk * 8;
                __builtin_amdgcn_global_load_lds((const __attribute__((address_space(1))) void*)g,
                                                 (__attribute__((address_space(3))) void*)(As + rbase * 32),
                                                 16, 0, 0);
            }
            {
                const __hip_bfloat16* g = B + (size_t)(bn * 128 + rbase + lrow) * Kp + k0 + lchk * 8;
                __builtin_amdgcn_global_load_lds((const __attribute__((address_space(1))) void*)g,
                                                 (__attribute__((address_space(3))) void*)(Bs + rbase * 32),
                                                 16, 0, 0);
            }
        }
        __syncthreads();

        short8 a[4], b[4];
#pragma unroll
        for (int i = 0; i < 4; ++i)
            a[i] = *reinterpret_cast<const short8*>(As + (wm * 64 + i * 16 + (lane & 15)) * 32 + (lane >> 4) * 8);
#pragma unroll
        for (int j = 0; j < 4; ++j)
            b[j] = *reinterpret_cast<const short8*>(Bs + (wn * 64 + j * 16 + (lane & 15)) * 32 + (lane >> 4) * 8);
#pragma unroll
        for (int i = 0; i < 4; ++i)
#pragma unroll
            for (int j = 0; j < 4; ++j)
                acc[i][j] = __builtin_amdgcn_mfma_f32_16x16x32_bf16(a[i], b[j], acc[i][j], 0, 0, 0);
        __syncthreads();
    }

    // C/D layout: col = lane&15, row = (lane>>4)*4 + reg
#pragma unroll
    for (int i = 0; i < 4; ++i) {
#pragma unroll
        for (int j = 0; j < 4; ++j) {
            const int col = bn * 128 + wn * 64 + j * 16 + (lane & 15);
#pragma unroll
            for (int r2 = 0; r2 < 4; ++r2) {
                const int row = bm * 128 + wm * 64 + i * 16 + (lane >> 4) * 4 + r2;
                C[(size_t)row * N + col] = __float2bfloat16(acc[i][j][r2]);
            }
        }
    }
}

// --- fractional LIF scan: time-tiled, batched-LDS-load memory term ----------
// One thread per neuron. History stored TRANSPOSED in LDS: hist[k][lane]
// (stride-1 across lanes -> 2-way bank aliasing = free; no cross-thread data,
// so no __syncthreads needed between tiles).
// Per tile of TB=16 steps:
//   old-phase: per 16-slot chunk, ALL 16 history reads are issued into an
//              explicit hv[16] register array BEFORE the 256-FMA block, so
//              the 16 ds_read latencies overlap each other and are covered by
//              the cw loads + FMA stream (single-wave latency hiding).
//   seq-phase: mem ready in old[i]; new dV scatter-forwarded to old[i'>i].
// Summation order per output is unchanged (k ascending, then within-tile).
// FINAL=false: Iin bf16, write spikes bf16 (for GEMM2)
// FINAL=true : Iin f32,  write spikes f32 + mems f32 (d_out)
template <bool FINAL>
__global__ __launch_bounds__(64) void flif_scan_kernel(const void* __restrict__ Iin,
                                                       void* __restrict__ spikes,
                                                       float* __restrict__ mems,
                                                       const float* __restrict__ ctab,
                                                       int NT, float kappa) {
    __shared__ float hist[T_STEPS * 64];        // [k][lane], 32 KB
    __shared__ __attribute__((aligned(16))) float cs[192];
    const int lane = threadIdx.x;
    const int nid  = blockIdx.x * 64 + lane;

    // prefetch tile-0 inputs before anything else (latency hidden by c-load+sync)
    float pfI[TB];
#pragma unroll
    for (int i = 0; i < TB; ++i) {
        if (FINAL) pfI[i] = ((const float*)Iin)[(size_t)i * NT + nid];
        else       pfI[i] = __bfloat162float(((const __hip_bfloat16*)Iin)[(size_t)i * NT + nid]);
    }

    for (int j = lane; j < 192; j += 64) cs[j] = ctab[j];
    __syncthreads();

    // small c window for within-tile terms (c[1..15]; index 0 unused)
    float cn[TB];
#pragma unroll
    for (int j = 0; j < TB; ++j) cn[j] = cs[j];

    float V = -70.f;

    for (int t = 0; t < T_STEPS / TB; ++t) {
        const int n0 = t * TB;              // 0-based step index base of this tile

        // refill input prefetch for this tile (issued early; latency hides
        // under the old-phase compute below)
        if (t > 0) {
#pragma unroll
            for (int i = 0; i < TB; ++i) {
                if (FINAL) pfI[i] = ((const float*)Iin)[(size_t)(n0 + i) * NT + nid];
                else       pfI[i] = __bfloat162float(((const __hip_bfloat16*)Iin)[(size_t)(n0 + i) * NT + nid]);
            }
        }

        float old_[TB];
#pragma unroll
        for (int i = 0; i < TB; ++i) old_[i] = 0.f;

        // ---- old-phase: chunks of 16 history slots, k ascending ----
        for (int k0 = 0; k0 < n0; k0 += 16) {
            // 1) batch-issue ALL 16 history reads (independent ds_read_b32,
            //    latencies overlap; base addr + kk*256B immediate offsets)
            float hv[16];
#pragma unroll
            for (int kk = 0; kk < 16; ++kk)
                hv[kk] = hist[(k0 + kk) * 64 + lane];

            // 2) c-window loads (broadcast ds_read_b128, cover hv tail)
            const int base = n0 - k0 - 15;  // >=1, and base-1 is a multiple of 16
            float cw[32];                   // cw[j] = c[base-1+j], j=0..31
#pragma unroll
            for (int q = 0; q < 8; ++q) {
                const float4 cv = *reinterpret_cast<const float4*>(cs + (base - 1) + 4 * q);
                cw[4 * q + 0] = cv.x; cw[4 * q + 1] = cv.y;
                cw[4 * q + 2] = cv.z; cw[4 * q + 3] = cv.w;
            }

            // 3) 256 independent FMAs, 16 parallel chains
#pragma unroll
            for (int kk = 0; kk < 16; ++kk) {
                // c[n0+i-(k0+kk)] = c[base-1 + (16-kk+i)]
#pragma unroll
                for (int i = 0; i < TB; ++i)
                    old_[i] += hv[kk] * cw[16 - kk + i];
            }
        }

        // ---- sequential phase: 16 steps, short critical chain ----
#pragma unroll
        for (int i = 0; i < TB; ++i) {
            const int nm1 = n0 + i;                       // 0-based step index
            const float Iv = pfI[i];
            const float f  = (-0.025f * (V + 70.f) + Iv) * 2.0f;   // /CM, CM=0.5
            const float Vn = kappa * f + V - old_[i];
            const bool  sp = (Vn >= -50.f);
            const float Vr = sp ? -70.f : Vn;
            const float dv = Vr - V;
            hist[nm1 * 64 + lane] = dv;
            // scatter-forward this dV into the remaining steps of the tile
#pragma unroll
            for (int i2 = i + 1; i2 < TB; ++i2)
                old_[i2] += dv * cn[i2 - i];
            if (FINAL) {
                ((float*)spikes)[(size_t)nm1 * NT + nid] = sp ? 1.f : 0.f;
                mems[(size_t)nm1 * NT + nid] = Vr;
            } else {
                ((__hip_bfloat16*)spikes)[(size_t)nm1 * NT + nid] = __float2bfloat16(sp ? 1.f : 0.f);
            }
            V = Vr;
        }
    }
}

// --- GEMM2: Io[r][o] = sum_h S[r][h]*Wo[o][h], one wave per row (f32 out) ---
__global__ __launch_bounds__(256) void gemm2_kernel(const __hip_bfloat16* __restrict__ S,
                                                    const float* __restrict__ Wo,
                                                    float* __restrict__ Io) {
    const int wave = threadIdx.x >> 6, lane = threadIdx.x & 63;
    const int r = blockIdx.x * 4 + wave;
    u16x8 raw = *reinterpret_cast<const u16x8*>(S + (size_t)r * NH + lane * 8);
    float s[8];
#pragma unroll
    for (int j = 0; j < 8; ++j) s[j] = b2f_bits(raw[j]);
#pragma unroll
    for (int o = 0; o < NO; ++o) {
        const float* w = Wo + (size_t)o * NH + lane * 8;
        float a = 0.f;
#pragma unroll
        for (int j = 0; j < 8; ++j) a += s[j] * w[j];
#pragma unroll
        for (int off = 32; off; off >>= 1) a += __shfl_xor(a, off);
        if (lane == o) Io[(size_t)r * NO + o] = a;
    }
}

extern "C" void kernel_launch(void* const* d_in, const int* in_sizes, int n_in,
                              void* d_out, int out_size, void* d_ws, size_t ws_size,
                              hipStream_t stream) {
    const float* data = (const float*)d_in[0];   // [64][128][784]
    const float* Wh   = (const float*)d_in[1];   // [512][784]
    const float* Wo   = (const float*)d_in[2];   // [10][512]
    float* out = (float*)d_out;                  // f32! spikes then mems

    char* ws = (char*)d_ws;
    size_t off = 0;
    auto alloc = [&](size_t bytes) { void* p = ws + off; off += (bytes + 255) & ~255ull; return p; };
    __hip_bfloat16* Ab   = (__hip_bfloat16*)alloc((size_t)M1 * NIP * 2);  // 13.1 MB
    __hip_bfloat16* Whb  = (__hip_bfloat16*)alloc((size_t)NH * NIP * 2);  // 0.8 MB
    __hip_bfloat16* Ih   = (__hip_bfloat16*)alloc((size_t)M1 * NH * 2);   // 8.4 MB
    __hip_bfloat16* Sh   = (__hip_bfloat16*)alloc((size_t)M1 * NH * 2);   // 8.4 MB
    float*          Io   = (float*)alloc((size_t)M1 * NO * 4);            // 0.33 MB
    float*          ctab = (float*)alloc(192 * 4);

    const float kappa = (float)(std::pow(0.1, 0.2) * std::tgamma(1.8));

    init_c_kernel<<<1, 256, 0, stream>>>(ctab);
    cast_pad_kernel<<<(M1 * 200 + 255) / 256, 256, 0, stream>>>(data, Ab, M1, 1);
    cast_pad_kernel<<<(NH * 200 + 255) / 256, 256, 0, stream>>>(Wh, Whb, NH, 0);

    dim3 g1(64, 4, 1);   // M/128 x N/128
    gemm_bf16_kernel<<<g1, 256, 0, stream>>>(Ab, Whb, Ih, NH, NIP);

    flif_scan_kernel<false><<<NT_H / 64, 64, 0, stream>>>(Ih, Sh, nullptr, ctab, NT_H, kappa);

    gemm2_kernel<<<M1 / 4, 256, 0, stream>>>(Sh, Wo, Io);

    flif_scan_kernel<true><<<NT_O / 64, 64, 0, stream>>>(Io, out, out + OUT_HALF, ctab, NT_O, kappa);
}

// Round 5
// 79.240 us; speedup vs baseline: 1.3323x; 1.3323x over previous
//
#include <hip/hip_runtime.h>
#include <hip/hip_bf16.h>
#include <cmath>

#define T_STEPS 128
#define BATCH   64
#define NI      784
#define NIP     800      // padded K (25 * 32)
#define NH      512
#define NO      10
#define M1      (T_STEPS*BATCH)       // 8192
#define NT_H    (BATCH*NH)            // 32768
#define NT_O    (BATCH*NO)            // 640
#define OUT_HALF (T_STEPS*BATCH*NO)   // 81920
#define TB      16                    // time-tile for the scan

typedef __attribute__((ext_vector_type(8))) short short8;
typedef __attribute__((ext_vector_type(4))) float f32x4;
typedef __attribute__((ext_vector_type(8))) unsigned short u16x8;

static __device__ __forceinline__ unsigned short f2b_bits(float x) {
    __hip_bfloat16 h = __float2bfloat16(x);
    return *reinterpret_cast<unsigned short*>(&h);
}
static __device__ __forceinline__ float b2f_bits(unsigned short u) {
    union { unsigned int i; float f; } v; v.i = ((unsigned int)u) << 16; return v.f;
}

// --- c table: c[j] = (j+1)^0.8 - j^0.8 --------------------------------------
__global__ void init_c_kernel(float* __restrict__ c) {
    int j = threadIdx.x;
    if (j < 192) {
        double a = pow((double)(j + 1), 0.8);
        double b = pow((double)j, 0.8);
        c[j] = (float)(a - b);
    }
}

// --- cast + pad f32 -> bf16, optional (b,t)->(t,b) row permute --------------
// dst [rows][800]; mode0: src [rows][784]; mode1: src data[b][t][784], dst row r=t*64+b
__global__ __launch_bounds__(256) void cast_pad_kernel(const float* __restrict__ src,
                                                       __hip_bfloat16* __restrict__ dst,
                                                       int rows, int mode) {
    int idx = blockIdx.x * 256 + threadIdx.x;
    if (idx >= rows * 200) return;
    int r  = idx / 200;
    int n4 = (idx - r * 200) * 4;
    int srow = r;
    if (mode == 1) { int t = r >> 6, b = r & 63; srow = b * T_STEPS + t; }
    ushort4 o;
    if (n4 < NI) {
        const float4 f = *reinterpret_cast<const float4*>(src + (size_t)srow * NI + n4);
        o.x = f2b_bits(f.x); o.y = f2b_bits(f.y); o.z = f2b_bits(f.z); o.w = f2b_bits(f.w);
    } else {
        o.x = o.y = o.z = o.w = 0;
    }
    *reinterpret_cast<ushort4*>(dst + (size_t)r * NIP + n4) = o;
}

// --- bf16 MFMA GEMM: C[M][N] = A[M][Kp] * B[N][Kp]^T  (both row-major) ------
// tile 128x128, 4 waves (2x2), each wave 64x64 = 4x4 frags of 16x16x32
__global__ __launch_bounds__(256) void gemm_bf16_kernel(const __hip_bfloat16* __restrict__ A,
                                                        const __hip_bfloat16* __restrict__ B,
                                                        __hip_bfloat16* __restrict__ C,
                                                        int N, int Kp) {
    __shared__ __hip_bfloat16 As[128 * 32];
    __shared__ __hip_bfloat16 Bs[128 * 32];
    const int tid  = threadIdx.x;
    const int wave = tid >> 6, lane = tid & 63;
    const int wm = wave >> 1, wn = wave & 1;
    const int bm = blockIdx.x, bn = blockIdx.y;
    const int lrow = lane >> 2;      // 0..15
    const int lchk = lane & 3;       // 0..3

    f32x4 acc[4][4] = {};

    for (int k0 = 0; k0 < Kp; k0 += 32) {
#pragma unroll
        for (int p = 0; p < 2; ++p) {
            const int rbase = p * 64 + wave * 16;
            {
                const __hip_bfloat16* g = A + (size_t)(bm * 128 + rbase + lrow) * Kp + k0 + lchk * 8;
                __builtin_amdgcn_global_load_lds((const __attribute__((address_space(1))) void*)g,
                                                 (__attribute__((address_space(3))) void*)(As + rbase * 32),
                                                 16, 0, 0);
            }
            {
                const __hip_bfloat16* g = B + (size_t)(bn * 128 + rbase + lrow) * Kp + k0 + lchk * 8;
                __builtin_amdgcn_global_load_lds((const __attribute__((address_space(1))) void*)g,
                                                 (__attribute__((address_space(3))) void*)(Bs + rbase * 32),
                                                 16, 0, 0);
            }
        }
        __syncthreads();

        short8 a[4], b[4];
#pragma unroll
        for (int i = 0; i < 4; ++i)
            a[i] = *reinterpret_cast<const short8*>(As + (wm * 64 + i * 16 + (lane & 15)) * 32 + (lane >> 4) * 8);
#pragma unroll
        for (int j = 0; j < 4; ++j)
            b[j] = *reinterpret_cast<const short8*>(Bs + (wn * 64 + j * 16 + (lane & 15)) * 32 + (lane >> 4) * 8);
#pragma unroll
        for (int i = 0; i < 4; ++i)
#pragma unroll
            for (int j = 0; j < 4; ++j)
                acc[i][j] = __builtin_amdgcn_mfma_f32_16x16x32_bf16(a[i], b[j], acc[i][j], 0, 0, 0);
        __syncthreads();
    }

    // C/D layout: col = lane&15, row = (lane>>4)*4 + reg
#pragma unroll
    for (int i = 0; i < 4; ++i) {
#pragma unroll
        for (int j = 0; j < 4; ++j) {
            const int col = bn * 128 + wn * 64 + j * 16 + (lane & 15);
#pragma unroll
            for (int r2 = 0; r2 < 4; ++r2) {
                const int row = bm * 128 + wm * 64 + i * 16 + (lane >> 4) * 4 + r2;
                C[(size_t)row * N + col] = __float2bfloat16(acc[i][j][r2]);
            }
        }
    }
}

// --- fractional LIF scan: time-tiled + exact zero-history sparsity gate -----
// One thread per neuron. History stored TRANSPOSED in LDS: hist[k][lane].
// Sparsity gates (bit-exact): dv terms that are exactly +0.0 contribute +0.0
// to the memory sum (x + 0.0*c == x in f32), so:
//   - wave-level outer gate: if NO lane of this wave has produced a nonzero
//     dv yet (dvbits OR-tracker), skip the whole old-phase for the tile;
//   - per-chunk gate: skip the 256-FMA block when the 16 hv are all zero
//     across the wave;
//   - per-step gate on the within-tile scatter.
// For general (non-saturated) inputs the dense path runs unchanged;
// summation order in the dense path is identical to the previous version.
// Next-tile input currents are prefetched one tile ahead (seq-phase covers
// the global-load latency).
// FINAL=false: Iin bf16, write spikes bf16 (for GEMM2)
// FINAL=true : Iin f32,  write spikes f32 + mems f32 (d_out)
template <bool FINAL>
__global__ __launch_bounds__(64) void flif_scan_kernel(const void* __restrict__ Iin,
                                                       void* __restrict__ spikes,
                                                       float* __restrict__ mems,
                                                       const float* __restrict__ ctab,
                                                       int NT, float kappa) {
    __shared__ float hist[T_STEPS * 64];        // [k][lane], 32 KB
    __shared__ __attribute__((aligned(16))) float cs[192];
    const int lane = threadIdx.x;
    const int nid  = blockIdx.x * 64 + lane;

    // prefetch tile-0 inputs before anything else (latency hidden by c-load+sync)
    float pfI[TB];
#pragma unroll
    for (int i = 0; i < TB; ++i) {
        if (FINAL) pfI[i] = ((const float*)Iin)[(size_t)i * NT + nid];
        else       pfI[i] = __bfloat162float(((const __hip_bfloat16*)Iin)[(size_t)i * NT + nid]);
    }

    for (int j = lane; j < 192; j += 64) cs[j] = ctab[j];
    __syncthreads();

    // small c window for within-tile terms (c[1..15]; index 0 unused)
    float cn[TB];
#pragma unroll
    for (int j = 0; j < TB; ++j) cn[j] = cs[j];

    float V = -70.f;
    unsigned dvbits = 0u;     // OR of all dv bit patterns produced so far

    for (int t = 0; t < T_STEPS / TB; ++t) {
        const int n0 = t * TB;              // 0-based step index base of this tile

        float old_[TB];
#pragma unroll
        for (int i = 0; i < TB; ++i) old_[i] = 0.f;

        // ---- old-phase: wave-uniform skip when all history is exactly zero ----
        if (__any(dvbits != 0u)) {
            for (int k0 = 0; k0 < n0; k0 += 16) {
                // batch-issue ALL 16 history reads
                float hv[16];
                unsigned sb = 0u;
#pragma unroll
                for (int kk = 0; kk < 16; ++kk) {
                    hv[kk] = hist[(k0 + kk) * 64 + lane];
                    sb |= __float_as_uint(hv[kk]);
                }
                // per-chunk gate: all-zero chunk contributes exactly +0.0
                if (__any(sb != 0u)) {
                    const int base = n0 - k0 - 15;  // >=1, base-1 multiple of 16
                    float cw[32];                   // cw[j] = c[base-1+j]
#pragma unroll
                    for (int q = 0; q < 8; ++q) {
                        const float4 cv = *reinterpret_cast<const float4*>(cs + (base - 1) + 4 * q);
                        cw[4 * q + 0] = cv.x; cw[4 * q + 1] = cv.y;
                        cw[4 * q + 2] = cv.z; cw[4 * q + 3] = cv.w;
                    }
#pragma unroll
                    for (int kk = 0; kk < 16; ++kk) {
                        // c[n0+i-(k0+kk)] = c[base-1 + (16-kk+i)]
#pragma unroll
                        for (int i = 0; i < TB; ++i)
                            old_[i] += hv[kk] * cw[16 - kk + i];
                    }
                }
            }
        }

        // ---- prefetch NEXT tile's currents (seq-phase covers the latency) ----
        float pfN[TB];
        if (t + 1 < T_STEPS / TB) {
#pragma unroll
            for (int i = 0; i < TB; ++i) {
                const int s = n0 + TB + i;
                if (FINAL) pfN[i] = ((const float*)Iin)[(size_t)s * NT + nid];
                else       pfN[i] = __bfloat162float(((const __hip_bfloat16*)Iin)[(size_t)s * NT + nid]);
            }
        }

        // ---- sequential phase: 16 steps, short critical chain ----
#pragma unroll
        for (int i = 0; i < TB; ++i) {
            const int nm1 = n0 + i;                       // 0-based step index
            const float Iv = pfI[i];
            const float f  = (-0.025f * (V + 70.f) + Iv) * 2.0f;   // /CM, CM=0.5
            const float Vn = kappa * f + V - old_[i];
            const bool  sp = (Vn >= -50.f);
            const float Vr = sp ? -70.f : Vn;
            const float dv = Vr - V;
            hist[nm1 * 64 + lane] = dv;
            dvbits |= __float_as_uint(dv);
            // scatter-forward this dV into the remaining steps of the tile
            // (skipped exactly when dv == +0.0 across the wave)
            if (__any(__float_as_uint(dv) != 0u)) {
#pragma unroll
                for (int i2 = i + 1; i2 < TB; ++i2)
                    old_[i2] += dv * cn[i2 - i];
            }
            if (FINAL) {
                ((float*)spikes)[(size_t)nm1 * NT + nid] = sp ? 1.f : 0.f;
                mems[(size_t)nm1 * NT + nid] = Vr;
            } else {
                ((__hip_bfloat16*)spikes)[(size_t)nm1 * NT + nid] = __float2bfloat16(sp ? 1.f : 0.f);
            }
            V = Vr;
        }

        // rotate prefetch buffer
        if (t + 1 < T_STEPS / TB) {
#pragma unroll
            for (int i = 0; i < TB; ++i) pfI[i] = pfN[i];
        }
    }
}

// --- GEMM2: Io[r][o] = sum_h S[r][h]*Wo[o][h], one wave per row (f32 out) ---
__global__ __launch_bounds__(256) void gemm2_kernel(const __hip_bfloat16* __restrict__ S,
                                                    const float* __restrict__ Wo,
                                                    float* __restrict__ Io) {
    const int wave = threadIdx.x >> 6, lane = threadIdx.x & 63;
    const int r = blockIdx.x * 4 + wave;
    u16x8 raw = *reinterpret_cast<const u16x8*>(S + (size_t)r * NH + lane * 8);
    float s[8];
#pragma unroll
    for (int j = 0; j < 8; ++j) s[j] = b2f_bits(raw[j]);
#pragma unroll
    for (int o = 0; o < NO; ++o) {
        const float* w = Wo + (size_t)o * NH + lane * 8;
        float a = 0.f;
#pragma unroll
        for (int j = 0; j < 8; ++j) a += s[j] * w[j];
#pragma unroll
        for (int off = 32; off; off >>= 1) a += __shfl_xor(a, off);
        if (lane == o) Io[(size_t)r * NO + o] = a;
    }
}

extern "C" void kernel_launch(void* const* d_in, const int* in_sizes, int n_in,
                              void* d_out, int out_size, void* d_ws, size_t ws_size,
                              hipStream_t stream) {
    const float* data = (const float*)d_in[0];   // [64][128][784]
    const float* Wh   = (const float*)d_in[1];   // [512][784]
    const float* Wo   = (const float*)d_in[2];   // [10][512]
    float* out = (float*)d_out;                  // f32! spikes then mems

    char* ws = (char*)d_ws;
    size_t off = 0;
    auto alloc = [&](size_t bytes) { void* p = ws + off; off += (bytes + 255) & ~255ull; return p; };
    __hip_bfloat16* Ab   = (__hip_bfloat16*)alloc((size_t)M1 * NIP * 2);  // 13.1 MB
    __hip_bfloat16* Whb  = (__hip_bfloat16*)alloc((size_t)NH * NIP * 2);  // 0.8 MB
    __hip_bfloat16* Ih   = (__hip_bfloat16*)alloc((size_t)M1 * NH * 2);   // 8.4 MB
    __hip_bfloat16* Sh   = (__hip_bfloat16*)alloc((size_t)M1 * NH * 2);   // 8.4 MB
    float*          Io   = (float*)alloc((size_t)M1 * NO * 4);            // 0.33 MB
    float*          ctab = (float*)alloc(192 * 4);

    const float kappa = (float)(std::pow(0.1, 0.2) * std::tgamma(1.8));

    init_c_kernel<<<1, 256, 0, stream>>>(ctab);
    cast_pad_kernel<<<(M1 * 200 + 255) / 256, 256, 0, stream>>>(data, Ab, M1, 1);
    cast_pad_kernel<<<(NH * 200 + 255) / 256, 256, 0, stream>>>(Wh, Whb, NH, 0);

    dim3 g1(64, 4, 1);   // M/128 x N/128
    gemm_bf16_kernel<<<g1, 256, 0, stream>>>(Ab, Whb, Ih, NH, NIP);

    flif_scan_kernel<false><<<NT_H / 64, 64, 0, stream>>>(Ih, Sh, nullptr, ctab, NT_H, kappa);

    gemm2_kernel<<<M1 / 4, 256, 0, stream>>>(Sh, Wo, Io);

    flif_scan_kernel<true><<<NT_O / 64, 64, 0, stream>>>(Io, out, out + OUT_HALF, ctab, NT_O, kappa);
}

// Round 6
// 77.164 us; speedup vs baseline: 1.3681x; 1.0269x over previous
//
#include <hip/hip_runtime.h>
#include <hip/hip_bf16.h>
#include <cmath>

#define T_STEPS 128
#define BATCH   64
#define NI      784
#define NIP     800      // padded K (25 * 32)
#define NH      512
#define NO      10
#define M1      (T_STEPS*BATCH)       // 8192
#define NT_H    (BATCH*NH)            // 32768
#define NT_O    (BATCH*NO)            // 640
#define OUT_HALF (T_STEPS*BATCH*NO)   // 81920
#define TB      8                     // time-tile for the scan (small => regs stay in VGPRs)

typedef __attribute__((ext_vector_type(8))) short short8;
typedef __attribute__((ext_vector_type(4))) float f32x4;
typedef __attribute__((ext_vector_type(8))) unsigned short u16x8;

static __device__ __forceinline__ unsigned short f2b_bits(float x) {
    __hip_bfloat16 h = __float2bfloat16(x);
    return *reinterpret_cast<unsigned short*>(&h);
}
static __device__ __forceinline__ float b2f_bits(unsigned short u) {
    union { unsigned int i; float f; } v; v.i = ((unsigned int)u) << 16; return v.f;
}

// --- c table: c[j] = (j+1)^0.8 - j^0.8 --------------------------------------
__global__ void init_c_kernel(float* __restrict__ c) {
    int j = threadIdx.x;
    if (j < 192) {
        double a = pow((double)(j + 1), 0.8);
        double b = pow((double)j, 0.8);
        c[j] = (float)(a - b);
    }
}

// --- cast + pad f32 -> bf16, optional (b,t)->(t,b) row permute --------------
// dst [rows][800]; mode0: src [rows][784]; mode1: src data[b][t][784], dst row r=t*64+b
__global__ __launch_bounds__(256) void cast_pad_kernel(const float* __restrict__ src,
                                                       __hip_bfloat16* __restrict__ dst,
                                                       int rows, int mode) {
    int idx = blockIdx.x * 256 + threadIdx.x;
    if (idx >= rows * 200) return;
    int r  = idx / 200;
    int n4 = (idx - r * 200) * 4;
    int srow = r;
    if (mode == 1) { int t = r >> 6, b = r & 63; srow = b * T_STEPS + t; }
    ushort4 o;
    if (n4 < NI) {
        const float4 f = *reinterpret_cast<const float4*>(src + (size_t)srow * NI + n4);
        o.x = f2b_bits(f.x); o.y = f2b_bits(f.y); o.z = f2b_bits(f.z); o.w = f2b_bits(f.w);
    } else {
        o.x = o.y = o.z = o.w = 0;
    }
    *reinterpret_cast<ushort4*>(dst + (size_t)r * NIP + n4) = o;
}

// --- bf16 MFMA GEMM: C[M][N] = A[M][Kp] * B[N][Kp]^T  (both row-major) ------
// 64x64 tile, 4 waves (2x2), each wave 32x32 = 2x2 frags of 16x16x32.
// grid (M/64, N/64) = (128, 8) -> 1024 blocks = 4 blocks/CU: TLP hides the
// single-buffered staging latency (1-block/CU 128x128 version serialized a
// full HBM drain per K-step). Linear block id = bm + 128*bn; 128%8==0 so all
// bn-blocks sharing a bm land on one XCD -> A-band re-reads are L2-local.
__global__ __launch_bounds__(256) void gemm_bf16_kernel(const __hip_bfloat16* __restrict__ A,
                                                        const __hip_bfloat16* __restrict__ B,
                                                        __hip_bfloat16* __restrict__ C,
                                                        int N, int Kp) {
    __shared__ __hip_bfloat16 As[64 * 32];
    __shared__ __hip_bfloat16 Bs[64 * 32];
    const int tid  = threadIdx.x;
    const int wave = tid >> 6, lane = tid & 63;
    const int wm = wave >> 1, wn = wave & 1;
    const int bm = blockIdx.x, bn = blockIdx.y;
    const int lrow = lane >> 2;      // 0..15
    const int lchk = lane & 3;       // 0..3

    f32x4 acc[2][2] = {};

    for (int k0 = 0; k0 < Kp; k0 += 32) {
        // wave w stages rows w*16..w*16+15 of both tiles (lds dest is
        // wave-uniform base + lane*16B; per-lane global src matches that order)
        {
            const __hip_bfloat16* g = A + (size_t)(bm * 64 + wave * 16 + lrow) * Kp + k0 + lchk * 8;
            __builtin_amdgcn_global_load_lds((const __attribute__((address_space(1))) void*)g,
                                             (__attribute__((address_space(3))) void*)(As + wave * 512),
                                             16, 0, 0);
        }
        {
            const __hip_bfloat16* g = B + (size_t)(bn * 64 + wave * 16 + lrow) * Kp + k0 + lchk * 8;
            __builtin_amdgcn_global_load_lds((const __attribute__((address_space(1))) void*)g,
                                             (__attribute__((address_space(3))) void*)(Bs + wave * 512),
                                             16, 0, 0);
        }
        __syncthreads();

        short8 a[2], b[2];
#pragma unroll
        for (int i = 0; i < 2; ++i)
            a[i] = *reinterpret_cast<const short8*>(As + (wm * 32 + i * 16 + (lane & 15)) * 32 + (lane >> 4) * 8);
#pragma unroll
        for (int j = 0; j < 2; ++j)
            b[j] = *reinterpret_cast<const short8*>(Bs + (wn * 32 + j * 16 + (lane & 15)) * 32 + (lane >> 4) * 8);
#pragma unroll
        for (int i = 0; i < 2; ++i)
#pragma unroll
            for (int j = 0; j < 2; ++j)
                acc[i][j] = __builtin_amdgcn_mfma_f32_16x16x32_bf16(a[i], b[j], acc[i][j], 0, 0, 0);
        __syncthreads();
    }

    // C/D layout: col = lane&15, row = (lane>>4)*4 + reg
#pragma unroll
    for (int i = 0; i < 2; ++i) {
#pragma unroll
        for (int j = 0; j < 2; ++j) {
            const int col = bn * 64 + wn * 32 + j * 16 + (lane & 15);
#pragma unroll
            for (int r2 = 0; r2 < 4; ++r2) {
                const int row = bm * 64 + wm * 32 + i * 16 + (lane >> 4) * 4 + r2;
                C[(size_t)row * N + col] = __float2bfloat16(acc[i][j][r2]);
            }
        }
    }
}

// --- fractional LIF scan: TB=8 time-tiles, slim register footprint ----------
// One thread per neuron; history transposed in LDS hist[k][lane].
// Live register arrays per thread: pfI[8]+pfN[8]+old_[8]+cn[8] (+hv[8]/cw[16]
// in the dense old-phase) -- small enough that SROA keeps them in VGPRs
// (TB=16 version risked the scratch cliff seen in rounds 1-2).
// Gates (bit-exact; c[j]>0 and x-x=+0 so -0.0 never arises in hist/old_):
//   - wave outer gate skips the whole old-phase while all history dv==+0.0,
//   - per-chunk gate skips all-zero chunks in the dense path.
// Within-tile scatter is BRANCHLESS (always-add, exactly like the reference).
// FINAL=false: Iin bf16, write spikes bf16 (for GEMM2)
// FINAL=true : Iin f32,  write spikes f32 + mems f32 (d_out)
template <bool FINAL>
__global__ __launch_bounds__(64) void flif_scan_kernel(const void* __restrict__ Iin,
                                                       void* __restrict__ spikes,
                                                       float* __restrict__ mems,
                                                       const float* __restrict__ ctab,
                                                       int NT, float kappa) {
    __shared__ float hist[T_STEPS * 64];        // [k][lane], 32 KB
    __shared__ __attribute__((aligned(16))) float cs[192];
    const int lane = threadIdx.x;
    const int nid  = blockIdx.x * 64 + lane;

    // prefetch tile-0 inputs (latency hidden by c-load + sync)
    float pfI[TB];
#pragma unroll
    for (int i = 0; i < TB; ++i) {
        if (FINAL) pfI[i] = ((const float*)Iin)[(size_t)i * NT + nid];
        else       pfI[i] = __bfloat162float(((const __hip_bfloat16*)Iin)[(size_t)i * NT + nid]);
    }

    for (int j = lane; j < 192; j += 64) cs[j] = ctab[j];
    __syncthreads();

    // c window for within-tile scatter (c[1..7]; index 0 unused)
    float cn[TB];
#pragma unroll
    for (int j = 0; j < TB; ++j) cn[j] = cs[j];

    float V = -70.f;
    unsigned dvbits = 0u;     // OR of all dv bit patterns produced so far

    for (int t = 0; t < T_STEPS / TB; ++t) {
        const int n0 = t * TB;              // 0-based step index base of this tile

        float old_[TB];
#pragma unroll
        for (int i = 0; i < TB; ++i) old_[i] = 0.f;

        // ---- old-phase: skipped (bit-exactly) while history is all +0.0 ----
        if (__any(dvbits != 0u)) {
            for (int k0 = 0; k0 < n0; k0 += TB) {
                float hv[TB];
                unsigned sb = 0u;
#pragma unroll
                for (int kk = 0; kk < TB; ++kk) {
                    hv[kk] = hist[(k0 + kk) * 64 + lane];
                    sb |= __float_as_uint(hv[kk]);
                }
                if (__any(sb != 0u)) {
                    const int base = n0 - k0 - (TB - 1);   // >=1; base-1 multiple of 8
                    float cw[2 * TB];                      // cw[j] = c[base-1+j]
#pragma unroll
                    for (int q = 0; q < 4; ++q) {
                        const float4 cv = *reinterpret_cast<const float4*>(cs + (base - 1) + 4 * q);
                        cw[4 * q + 0] = cv.x; cw[4 * q + 1] = cv.y;
                        cw[4 * q + 2] = cv.z; cw[4 * q + 3] = cv.w;
                    }
#pragma unroll
                    for (int kk = 0; kk < TB; ++kk) {
                        // c[n0+i-(k0+kk)] = cw[TB-kk+i]
#pragma unroll
                        for (int i = 0; i < TB; ++i)
                            old_[i] += hv[kk] * cw[TB - kk + i];
                    }
                }
            }
        }

        // ---- prefetch NEXT tile's currents (seq-phase covers the latency) ----
        float pfN[TB];
        if (t + 1 < T_STEPS / TB) {
#pragma unroll
            for (int i = 0; i < TB; ++i) {
                const int s = n0 + TB + i;
                if (FINAL) pfN[i] = ((const float*)Iin)[(size_t)s * NT + nid];
                else       pfN[i] = __bfloat162float(((const __hip_bfloat16*)Iin)[(size_t)s * NT + nid]);
            }
        }

        // ---- sequential phase: TB steps, short critical chain ----
#pragma unroll
        for (int i = 0; i < TB; ++i) {
            const int nm1 = n0 + i;                       // 0-based step index
            const float Iv = pfI[i];
            const float f  = (-0.025f * (V + 70.f) + Iv) * 2.0f;   // /CM, CM=0.5
            const float Vn = kappa * f + V - old_[i];
            const bool  sp = (Vn >= -50.f);
            const float Vr = sp ? -70.f : Vn;
            const float dv = Vr - V;
            hist[nm1 * 64 + lane] = dv;
            dvbits |= __float_as_uint(dv);
            // branchless scatter-forward (reference always adds these terms)
#pragma unroll
            for (int i2 = i + 1; i2 < TB; ++i2)
                old_[i2] += dv * cn[i2 - i];
            if (FINAL) {
                ((float*)spikes)[(size_t)nm1 * NT + nid] = sp ? 1.f : 0.f;
                mems[(size_t)nm1 * NT + nid] = Vr;
            } else {
                ((__hip_bfloat16*)spikes)[(size_t)nm1 * NT + nid] = __float2bfloat16(sp ? 1.f : 0.f);
            }
            V = Vr;
        }

        // rotate prefetch buffer
        if (t + 1 < T_STEPS / TB) {
#pragma unroll
            for (int i = 0; i < TB; ++i) pfI[i] = pfN[i];
        }
    }
}

// --- GEMM2: Io[r][o] = sum_h S[r][h]*Wo[o][h] -------------------------------
// 4 rows per wave; Wo slice hoisted to registers ONCE per wave (80 VGPRs) ->
// 4x less redundant Wo L2 traffic. Dot + butterfly order identical to before.
__global__ __launch_bounds__(256) void gemm2_kernel(const __hip_bfloat16* __restrict__ S,
                                                    const float* __restrict__ Wo,
                                                    float* __restrict__ Io) {
    const int wave = threadIdx.x >> 6, lane = threadIdx.x & 63;
    const int r0 = (blockIdx.x * 4 + wave) * 4;

    float wreg[NO][8];
#pragma unroll
    for (int o = 0; o < NO; ++o) {
        const float4 w0 = *reinterpret_cast<const float4*>(Wo + (size_t)o * NH + lane * 8);
        const float4 w1 = *reinterpret_cast<const float4*>(Wo + (size_t)o * NH + lane * 8 + 4);
        wreg[o][0] = w0.x; wreg[o][1] = w0.y; wreg[o][2] = w0.z; wreg[o][3] = w0.w;
        wreg[o][4] = w1.x; wreg[o][5] = w1.y; wreg[o][6] = w1.z; wreg[o][7] = w1.w;
    }

#pragma unroll
    for (int rr = 0; rr < 4; ++rr) {
        const int r = r0 + rr;
        u16x8 raw = *reinterpret_cast<const u16x8*>(S + (size_t)r * NH + lane * 8);
        float s[8];
#pragma unroll
        for (int j = 0; j < 8; ++j) s[j] = b2f_bits(raw[j]);
#pragma unroll
        for (int o = 0; o < NO; ++o) {
            float a = 0.f;
#pragma unroll
            for (int j = 0; j < 8; ++j) a += s[j] * wreg[o][j];
#pragma unroll
            for (int off = 32; off; off >>= 1) a += __shfl_xor(a, off);
            if (lane == o) Io[(size_t)r * NO + o] = a;
        }
    }
}

extern "C" void kernel_launch(void* const* d_in, const int* in_sizes, int n_in,
                              void* d_out, int out_size, void* d_ws, size_t ws_size,
                              hipStream_t stream) {
    const float* data = (const float*)d_in[0];   // [64][128][784]
    const float* Wh   = (const float*)d_in[1];   // [512][784]
    const float* Wo   = (const float*)d_in[2];   // [10][512]
    float* out = (float*)d_out;                  // f32! spikes then mems

    char* ws = (char*)d_ws;
    size_t off = 0;
    auto alloc = [&](size_t bytes) { void* p = ws + off; off += (bytes + 255) & ~255ull; return p; };
    __hip_bfloat16* Ab   = (__hip_bfloat16*)alloc((size_t)M1 * NIP * 2);  // 13.1 MB
    __hip_bfloat16* Whb  = (__hip_bfloat16*)alloc((size_t)NH * NIP * 2);  // 0.8 MB
    __hip_bfloat16* Ih   = (__hip_bfloat16*)alloc((size_t)M1 * NH * 2);   // 8.4 MB
    __hip_bfloat16* Sh   = (__hip_bfloat16*)alloc((size_t)M1 * NH * 2);   // 8.4 MB
    float*          Io   = (float*)alloc((size_t)M1 * NO * 4);            // 0.33 MB
    float*          ctab = (float*)alloc(192 * 4);

    const float kappa = (float)(std::pow(0.1, 0.2) * std::tgamma(1.8));

    init_c_kernel<<<1, 256, 0, stream>>>(ctab);
    cast_pad_kernel<<<(M1 * 200 + 255) / 256, 256, 0, stream>>>(data, Ab, M1, 1);
    cast_pad_kernel<<<(NH * 200 + 255) / 256, 256, 0, stream>>>(Wh, Whb, NH, 0);

    dim3 g1(M1 / 64, NH / 64, 1);   // (128, 8)
    gemm_bf16_kernel<<<g1, 256, 0, stream>>>(Ab, Whb, Ih, NH, NIP);

    flif_scan_kernel<false><<<NT_H / 64, 64, 0, stream>>>(Ih, Sh, nullptr, ctab, NT_H, kappa);

    gemm2_kernel<<<M1 / 16, 256, 0, stream>>>(Sh, Wo, Io);

    flif_scan_kernel<true><<<NT_O / 64, 64, 0, stream>>>(Io, out, out + OUT_HALF, ctab, NT_O, kappa);
}

// Round 7
// 74.040 us; speedup vs baseline: 1.4258x; 1.0422x over previous
//
#include <hip/hip_runtime.h>
#include <hip/hip_bf16.h>
#include <cmath>

#define T_STEPS 128
#define BATCH   64
#define NI      784
#define NIP     800      // padded K (25 * 32)
#define NH      512
#define NO      10
#define M1      (T_STEPS*BATCH)       // 8192
#define NT_H    (BATCH*NH)            // 32768
#define NT_O    (BATCH*NO)            // 640
#define OUT_HALF (T_STEPS*BATCH*NO)   // 81920
#define TB      8                     // time-tile for the scan

typedef __attribute__((ext_vector_type(8))) short short8;
typedef __attribute__((ext_vector_type(4))) float f32x4;
typedef __attribute__((ext_vector_type(8))) unsigned short u16x8;

static __device__ __forceinline__ unsigned short f2b_bits(float x) {
    __hip_bfloat16 h = __float2bfloat16(x);
    return *reinterpret_cast<unsigned short*>(&h);
}
static __device__ __forceinline__ float b2f_bits(unsigned short u) {
    union { unsigned int i; float f; } v; v.i = ((unsigned int)u) << 16; return v.f;
}

// --- prep: fused ctab init + data cast/permute + Wh cast --------------------
// block 0        : ctab[j] = (j+1)^0.8 - j^0.8
// blocks 1..6400 : data [64][128][784] f32 -> Ab [8192][800] bf16, row r=t*64+b
// blocks 6401..  : Wh [512][784] f32 -> Whb [512][800] bf16
__global__ __launch_bounds__(256) void prep_kernel(const float* __restrict__ data,
                                                   const float* __restrict__ Wh,
                                                   __hip_bfloat16* __restrict__ Ab,
                                                   __hip_bfloat16* __restrict__ Whb,
                                                   float* __restrict__ ctab) {
    const int bid = blockIdx.x;
    if (bid == 0) {
        const int j = threadIdx.x;
        if (j < 192) {
            double a = pow((double)(j + 1), 0.8);
            double b = pow((double)j, 0.8);
            ctab[j] = (float)(a - b);
        }
        return;
    }
    if (bid <= 6400) {
        const int idx = (bid - 1) * 256 + threadIdx.x;      // < M1*200 exactly
        const int r  = idx / 200;
        const int n4 = (idx - r * 200) * 4;
        const int t = r >> 6, b = r & 63;
        const int srow = b * T_STEPS + t;
        ushort4 o;
        if (n4 < NI) {
            const float4 f = *reinterpret_cast<const float4*>(data + (size_t)srow * NI + n4);
            o.x = f2b_bits(f.x); o.y = f2b_bits(f.y); o.z = f2b_bits(f.z); o.w = f2b_bits(f.w);
        } else {
            o.x = o.y = o.z = o.w = 0;
        }
        *reinterpret_cast<ushort4*>(Ab + (size_t)r * NIP + n4) = o;
    } else {
        const int idx = (bid - 6401) * 256 + threadIdx.x;   // < NH*200 exactly
        const int r  = idx / 200;
        const int n4 = (idx - r * 200) * 4;
        ushort4 o;
        if (n4 < NI) {
            const float4 f = *reinterpret_cast<const float4*>(Wh + (size_t)r * NI + n4);
            o.x = f2b_bits(f.x); o.y = f2b_bits(f.y); o.z = f2b_bits(f.z); o.w = f2b_bits(f.w);
        } else {
            o.x = o.y = o.z = o.w = 0;
        }
        *reinterpret_cast<ushort4*>(Whb + (size_t)r * NIP + n4) = o;
    }
}

// --- bf16 MFMA GEMM: C[M][N] = A[M][Kp] * B[N][Kp]^T  (both row-major) ------
// PROVEN round-0/1 config: tile 128x128, 4 waves (2x2), each wave 64x64 =
// 4x4 frags of 16x16x32. (64x64 retile in round 6 was unverified; reverted.)
__global__ __launch_bounds__(256) void gemm_bf16_kernel(const __hip_bfloat16* __restrict__ A,
                                                        const __hip_bfloat16* __restrict__ B,
                                                        __hip_bfloat16* __restrict__ C,
                                                        int N, int Kp) {
    __shared__ __hip_bfloat16 As[128 * 32];
    __shared__ __hip_bfloat16 Bs[128 * 32];
    const int tid  = threadIdx.x;
    const int wave = tid >> 6, lane = tid & 63;
    const int wm = wave >> 1, wn = wave & 1;
    const int bm = blockIdx.x, bn = blockIdx.y;
    const int lrow = lane >> 2;      // 0..15
    const int lchk = lane & 3;       // 0..3

    f32x4 acc[4][4] = {};

    for (int k0 = 0; k0 < Kp; k0 += 32) {
#pragma unroll
        for (int p = 0; p < 2; ++p) {
            const int rbase = p * 64 + wave * 16;
            {
                const __hip_bfloat16* g = A + (size_t)(bm * 128 + rbase + lrow) * Kp + k0 + lchk * 8;
                __builtin_amdgcn_global_load_lds((const __attribute__((address_space(1))) void*)g,
                                                 (__attribute__((address_space(3))) void*)(As + rbase * 32),
                                                 16, 0, 0);
            }
            {
                const __hip_bfloat16* g = B + (size_t)(bn * 128 + rbase + lrow) * Kp + k0 + lchk * 8;
                __builtin_amdgcn_global_load_lds((const __attribute__((address_space(1))) void*)g,
                                                 (__attribute__((address_space(3))) void*)(Bs + rbase * 32),
                                                 16, 0, 0);
            }
        }
        __syncthreads();

        short8 a[4], b[4];
#pragma unroll
        for (int i = 0; i < 4; ++i)
            a[i] = *reinterpret_cast<const short8*>(As + (wm * 64 + i * 16 + (lane & 15)) * 32 + (lane >> 4) * 8);
#pragma unroll
        for (int j = 0; j < 4; ++j)
            b[j] = *reinterpret_cast<const short8*>(Bs + (wn * 64 + j * 16 + (lane & 15)) * 32 + (lane >> 4) * 8);
#pragma unroll
        for (int i = 0; i < 4; ++i)
#pragma unroll
            for (int j = 0; j < 4; ++j)
                acc[i][j] = __builtin_amdgcn_mfma_f32_16x16x32_bf16(a[i], b[j], acc[i][j], 0, 0, 0);
        __syncthreads();
    }

    // C/D layout: col = lane&15, row = (lane>>4)*4 + reg
#pragma unroll
    for (int i = 0; i < 4; ++i) {
#pragma unroll
        for (int j = 0; j < 4; ++j) {
            const int col = bn * 128 + wn * 64 + j * 16 + (lane & 15);
#pragma unroll
            for (int r2 = 0; r2 < 4; ++r2) {
                const int row = bm * 128 + wm * 64 + i * 16 + (lane >> 4) * 4 + r2;
                C[(size_t)row * N + col] = __float2bfloat16(acc[i][j][r2]);
            }
        }
    }
}

// --- fractional LIF scan: TB=8 tiles + zero-history gate + LDS input stage --
// One thread per neuron; history transposed in LDS hist[k][lane].
// !FINAL: the ENTIRE input block [128 steps][64 neurons] (16 KB bf16) is
//   staged into LDS via 16x global_load_lds_dwordx4 at kernel start; the one
//   vmcnt(0) drain at the following __syncthreads pays all HBM latency once
//   (removes 16 per-tile global-load latency exposures). Seq-phase reads
//   inputs from LDS (2B stride across lanes = 2-way bank alias = free).
// FINAL: register double-buffer prefetch (64 KB LDS staging wouldn't fit;
//   only 10 blocks, Io is small/L2-warm).
// Gates (bit-exact: adding terms that are exactly +0.0 preserves bits; dv is
//   x-x=+0 or negative, never -0 summed): wave-level outer gate skips the
//   old-phase while all history dv==+0.0; per-chunk gate in the dense path.
// Within-tile scatter is branchless (always-add, like the reference).
template <bool FINAL>
__global__ __launch_bounds__(64) void flif_scan_kernel(const void* __restrict__ Iin,
                                                       void* __restrict__ spikes,
                                                       float* __restrict__ mems,
                                                       const float* __restrict__ ctab,
                                                       int NT, float kappa) {
    __shared__ float hist[T_STEPS * 64];        // [k][lane], 32 KB
    __shared__ __attribute__((aligned(16))) float cs[192];
    __shared__ __attribute__((aligned(16))) __hip_bfloat16 inp[FINAL ? 64 : T_STEPS * 64];
    const int lane = threadIdx.x;
    const int nid  = blockIdx.x * 64 + lane;

    if constexpr (!FINAL) {
        // stage all inputs: 16 instrs, each 64 lanes x 16B = 8 rows of [64]bf16
        // lane l -> row q*8 + l/8, cols (l%8)*8..+7 ; dest byte q*1024 + l*16
#pragma unroll
        for (int q = 0; q < 16; ++q) {
            const __hip_bfloat16* g = (const __hip_bfloat16*)Iin +
                ((size_t)(q * 8 + (lane >> 3)) * NT + (size_t)blockIdx.x * 64 + (lane & 7) * 8);
            __builtin_amdgcn_global_load_lds((const __attribute__((address_space(1))) void*)g,
                                             (__attribute__((address_space(3))) void*)((char*)inp + q * 1024),
                                             16, 0, 0);
        }
    }

    float pfI[TB];
    if constexpr (FINAL) {
#pragma unroll
        for (int i = 0; i < TB; ++i)
            pfI[i] = ((const float*)Iin)[(size_t)i * NT + nid];
    }

    for (int j = lane; j < 192; j += 64) cs[j] = ctab[j];
    __syncthreads();   // also drains the global_load_lds staging (vmcnt 0)

    // c window for within-tile scatter (c[1..7]; index 0 unused)
    float cn[TB];
#pragma unroll
    for (int j = 0; j < TB; ++j) cn[j] = cs[j];

    float V = -70.f;
    unsigned dvbits = 0u;     // OR of all dv bit patterns produced so far

    for (int t = 0; t < T_STEPS / TB; ++t) {
        const int n0 = t * TB;              // 0-based step index base of this tile

        float old_[TB];
#pragma unroll
        for (int i = 0; i < TB; ++i) old_[i] = 0.f;

        // ---- old-phase: skipped (bit-exactly) while history is all +0.0 ----
        if (__any(dvbits != 0u)) {
            for (int k0 = 0; k0 < n0; k0 += TB) {
                float hv[TB];
                unsigned sb = 0u;
#pragma unroll
                for (int kk = 0; kk < TB; ++kk) {
                    hv[kk] = hist[(k0 + kk) * 64 + lane];
                    sb |= __float_as_uint(hv[kk]);
                }
                if (__any(sb != 0u)) {
                    const int base = n0 - k0 - (TB - 1);   // >=1; base-1 multiple of 8
                    float cw[2 * TB];                      // cw[j] = c[base-1+j]
#pragma unroll
                    for (int q = 0; q < 4; ++q) {
                        const float4 cv = *reinterpret_cast<const float4*>(cs + (base - 1) + 4 * q);
                        cw[4 * q + 0] = cv.x; cw[4 * q + 1] = cv.y;
                        cw[4 * q + 2] = cv.z; cw[4 * q + 3] = cv.w;
                    }
#pragma unroll
                    for (int kk = 0; kk < TB; ++kk) {
                        // c[n0+i-(k0+kk)] = cw[TB-kk+i]
#pragma unroll
                        for (int i = 0; i < TB; ++i)
                            old_[i] += hv[kk] * cw[TB - kk + i];
                    }
                }
            }
        }

        // ---- this tile's input currents ----
        float Ivv[TB];
        if constexpr (FINAL) {
#pragma unroll
            for (int i = 0; i < TB; ++i) Ivv[i] = pfI[i];
            if (t + 1 < T_STEPS / TB) {
#pragma unroll
                for (int i = 0; i < TB; ++i)
                    pfI[i] = ((const float*)Iin)[(size_t)(n0 + TB + i) * NT + nid];
            }
        } else {
#pragma unroll
            for (int i = 0; i < TB; ++i)
                Ivv[i] = __bfloat162float(inp[(n0 + i) * 64 + lane]);
        }

        // ---- sequential phase: TB steps, short critical chain ----
#pragma unroll
        for (int i = 0; i < TB; ++i) {
            const int nm1 = n0 + i;                       // 0-based step index
            const float Iv = Ivv[i];
            const float f  = (-0.025f * (V + 70.f) + Iv) * 2.0f;   // /CM, CM=0.5
            const float Vn = kappa * f + V - old_[i];
            const bool  sp = (Vn >= -50.f);
            const float Vr = sp ? -70.f : Vn;
            const float dv = Vr - V;
            hist[nm1 * 64 + lane] = dv;
            dvbits |= __float_as_uint(dv);
            // branchless scatter-forward (reference always adds these terms)
#pragma unroll
            for (int i2 = i + 1; i2 < TB; ++i2)
                old_[i2] += dv * cn[i2 - i];
            if (FINAL) {
                ((float*)spikes)[(size_t)nm1 * NT + nid] = sp ? 1.f : 0.f;
                mems[(size_t)nm1 * NT + nid] = Vr;
            } else {
                ((__hip_bfloat16*)spikes)[(size_t)nm1 * NT + nid] = __float2bfloat16(sp ? 1.f : 0.f);
            }
            V = Vr;
        }
    }
}

// --- GEMM2: Io[r][o] = sum_h S[r][h]*Wo[o][h] -------------------------------
// 4 rows per wave; Wo slice hoisted to registers once per wave.
__global__ __launch_bounds__(256) void gemm2_kernel(const __hip_bfloat16* __restrict__ S,
                                                    const float* __restrict__ Wo,
                                                    float* __restrict__ Io) {
    const int wave = threadIdx.x >> 6, lane = threadIdx.x & 63;
    const int r0 = (blockIdx.x * 4 + wave) * 4;

    float wreg[NO][8];
#pragma unroll
    for (int o = 0; o < NO; ++o) {
        const float4 w0 = *reinterpret_cast<const float4*>(Wo + (size_t)o * NH + lane * 8);
        const float4 w1 = *reinterpret_cast<const float4*>(Wo + (size_t)o * NH + lane * 8 + 4);
        wreg[o][0] = w0.x; wreg[o][1] = w0.y; wreg[o][2] = w0.z; wreg[o][3] = w0.w;
        wreg[o][4] = w1.x; wreg[o][5] = w1.y; wreg[o][6] = w1.z; wreg[o][7] = w1.w;
    }

#pragma unroll
    for (int rr = 0; rr < 4; ++rr) {
        const int r = r0 + rr;
        u16x8 raw = *reinterpret_cast<const u16x8*>(S + (size_t)r * NH + lane * 8);
        float s[8];
#pragma unroll
        for (int j = 0; j < 8; ++j) s[j] = b2f_bits(raw[j]);
#pragma unroll
        for (int o = 0; o < NO; ++o) {
            float a = 0.f;
#pragma unroll
            for (int j = 0; j < 8; ++j) a += s[j] * wreg[o][j];
#pragma unroll
            for (int off = 32; off; off >>= 1) a += __shfl_xor(a, off);
            if (lane == o) Io[(size_t)r * NO + o] = a;
        }
    }
}

extern "C" void kernel_launch(void* const* d_in, const int* in_sizes, int n_in,
                              void* d_out, int out_size, void* d_ws, size_t ws_size,
                              hipStream_t stream) {
    const float* data = (const float*)d_in[0];   // [64][128][784]
    const float* Wh   = (const float*)d_in[1];   // [512][784]
    const float* Wo   = (const float*)d_in[2];   // [10][512]
    float* out = (float*)d_out;                  // f32! spikes then mems

    char* ws = (char*)d_ws;
    size_t off = 0;
    auto alloc = [&](size_t bytes) { void* p = ws + off; off += (bytes + 255) & ~255ull; return p; };
    __hip_bfloat16* Ab   = (__hip_bfloat16*)alloc((size_t)M1 * NIP * 2);  // 13.1 MB
    __hip_bfloat16* Whb  = (__hip_bfloat16*)alloc((size_t)NH * NIP * 2);  // 0.8 MB
    __hip_bfloat16* Ih   = (__hip_bfloat16*)alloc((size_t)M1 * NH * 2);   // 8.4 MB
    __hip_bfloat16* Sh   = (__hip_bfloat16*)alloc((size_t)M1 * NH * 2);   // 8.4 MB
    float*          Io   = (float*)alloc((size_t)M1 * NO * 4);            // 0.33 MB
    float*          ctab = (float*)alloc(192 * 4);

    const float kappa = (float)(std::pow(0.1, 0.2) * std::tgamma(1.8));

    prep_kernel<<<6801, 256, 0, stream>>>(data, Wh, Ab, Whb, ctab);

    dim3 g1(M1 / 128, NH / 128, 1);   // (64, 4)
    gemm_bf16_kernel<<<g1, 256, 0, stream>>>(Ab, Whb, Ih, NH, NIP);

    flif_scan_kernel<false><<<NT_H / 64, 64, 0, stream>>>(Ih, Sh, nullptr, ctab, NT_H, kappa);

    gemm2_kernel<<<M1 / 16, 256, 0, stream>>>(Sh, Wo, Io);

    flif_scan_kernel<true><<<NT_O / 64, 64, 0, stream>>>(Io, out, out + OUT_HALF, ctab, NT_O, kappa);
}

// Round 8
// 69.496 us; speedup vs baseline: 1.5191x; 1.0654x over previous
//
#include <hip/hip_runtime.h>
#include <hip/hip_bf16.h>
#include <cmath>

#define T_STEPS 128
#define BATCH   64
#define NI      784
#define NIP     800      // padded K (25 * 32)
#define NH      512
#define NO      10
#define M1      (T_STEPS*BATCH)       // 8192
#define NT_H    (BATCH*NH)            // 32768
#define NT_O    (BATCH*NO)            // 640
#define OUT_HALF (T_STEPS*BATCH*NO)   // 81920
#define TB      8                     // time-tile for the scan

typedef __attribute__((ext_vector_type(8))) short short8;
typedef __attribute__((ext_vector_type(4))) float f32x4;
typedef __attribute__((ext_vector_type(8))) unsigned short u16x8;

static __device__ __forceinline__ unsigned short f2b_bits(float x) {
    __hip_bfloat16 h = __float2bfloat16(x);
    return *reinterpret_cast<unsigned short*>(&h);
}
static __device__ __forceinline__ float b2f_bits(unsigned short u) {
    union { unsigned int i; float f; } v; v.i = ((unsigned int)u) << 16; return v.f;
}

// --- prep: fused ctab init + data cast/permute + Wh cast --------------------
__global__ __launch_bounds__(256) void prep_kernel(const float* __restrict__ data,
                                                   const float* __restrict__ Wh,
                                                   __hip_bfloat16* __restrict__ Ab,
                                                   __hip_bfloat16* __restrict__ Whb,
                                                   float* __restrict__ ctab) {
    const int bid = blockIdx.x;
    if (bid == 0) {
        const int j = threadIdx.x;
        if (j < 192) {
            double a = pow((double)(j + 1), 0.8);
            double b = pow((double)j, 0.8);
            ctab[j] = (float)(a - b);
        }
        return;
    }
    if (bid <= 6400) {
        const int idx = (bid - 1) * 256 + threadIdx.x;      // < M1*200 exactly
        const int r  = idx / 200;
        const int n4 = (idx - r * 200) * 4;
        const int t = r >> 6, b = r & 63;
        const int srow = b * T_STEPS + t;
        ushort4 o;
        if (n4 < NI) {
            const float4 f = *reinterpret_cast<const float4*>(data + (size_t)srow * NI + n4);
            o.x = f2b_bits(f.x); o.y = f2b_bits(f.y); o.z = f2b_bits(f.z); o.w = f2b_bits(f.w);
        } else {
            o.x = o.y = o.z = o.w = 0;
        }
        *reinterpret_cast<ushort4*>(Ab + (size_t)r * NIP + n4) = o;
    } else {
        const int idx = (bid - 6401) * 256 + threadIdx.x;   // < NH*200 exactly
        const int r  = idx / 200;
        const int n4 = (idx - r * 200) * 4;
        ushort4 o;
        if (n4 < NI) {
            const float4 f = *reinterpret_cast<const float4*>(Wh + (size_t)r * NI + n4);
            o.x = f2b_bits(f.x); o.y = f2b_bits(f.y); o.z = f2b_bits(f.z); o.w = f2b_bits(f.w);
        } else {
            o.x = o.y = o.z = o.w = 0;
        }
        *reinterpret_cast<ushort4*>(Whb + (size_t)r * NIP + n4) = o;
    }
}

// --- bf16 MFMA GEMM, 128x128 tile, 2-phase pipelined staging ----------------
// Double-buffered LDS; next K-tile's global_load_lds are issued BEFORE the
// ds_read+MFMA work on the current tile, so MFMA covers part of the ~900-cyc
// HBM latency; the single __syncthreads (which drains vmcnt) moves the wait
// to AFTER compute instead of before it (T3 minimum 2-phase recipe).
__global__ __launch_bounds__(256) void gemm_bf16_kernel(const __hip_bfloat16* __restrict__ A,
                                                        const __hip_bfloat16* __restrict__ B,
                                                        __hip_bfloat16* __restrict__ C,
                                                        int N, int Kp) {
    __shared__ __hip_bfloat16 As[2][128 * 32];
    __shared__ __hip_bfloat16 Bs[2][128 * 32];
    const int tid  = threadIdx.x;
    const int wave = tid >> 6, lane = tid & 63;
    const int wm = wave >> 1, wn = wave & 1;
    const int bm = blockIdx.x, bn = blockIdx.y;
    const int lrow = lane >> 2;      // 0..15
    const int lchk = lane & 3;       // 0..3

    const int NTILES = Kp / 32;      // 25

    // stage K-tile tt into buffer buf
    auto STAGE = [&](int buf, int tt) {
        const int k0 = tt * 32;
#pragma unroll
        for (int p = 0; p < 2; ++p) {
            const int rbase = p * 64 + wave * 16;
            {
                const __hip_bfloat16* g = A + (size_t)(bm * 128 + rbase + lrow) * Kp + k0 + lchk * 8;
                __builtin_amdgcn_global_load_lds((const __attribute__((address_space(1))) void*)g,
                                                 (__attribute__((address_space(3))) void*)(As[buf] + rbase * 32),
                                                 16, 0, 0);
            }
            {
                const __hip_bfloat16* g = B + (size_t)(bn * 128 + rbase + lrow) * Kp + k0 + lchk * 8;
                __builtin_amdgcn_global_load_lds((const __attribute__((address_space(1))) void*)g,
                                                 (__attribute__((address_space(3))) void*)(Bs[buf] + rbase * 32),
                                                 16, 0, 0);
            }
        }
    };

    f32x4 acc[4][4] = {};

    STAGE(0, 0);
    __syncthreads();                 // drains vmcnt(0): buf0 ready

    int cur = 0;
    for (int t = 0; t < NTILES; ++t) {
        if (t + 1 < NTILES) STAGE(cur ^ 1, t + 1);   // loads in flight over MFMA

        short8 a[4], b[4];
#pragma unroll
        for (int i = 0; i < 4; ++i)
            a[i] = *reinterpret_cast<const short8*>(As[cur] + (wm * 64 + i * 16 + (lane & 15)) * 32 + (lane >> 4) * 8);
#pragma unroll
        for (int j = 0; j < 4; ++j)
            b[j] = *reinterpret_cast<const short8*>(Bs[cur] + (wn * 64 + j * 16 + (lane & 15)) * 32 + (lane >> 4) * 8);
#pragma unroll
        for (int i = 0; i < 4; ++i)
#pragma unroll
            for (int j = 0; j < 4; ++j)
                acc[i][j] = __builtin_amdgcn_mfma_f32_16x16x32_bf16(a[i], b[j], acc[i][j], 0, 0, 0);

        __syncthreads();             // drains next-tile loads + all reads of cur
        cur ^= 1;
    }

    // C/D layout: col = lane&15, row = (lane>>4)*4 + reg
#pragma unroll
    for (int i = 0; i < 4; ++i) {
#pragma unroll
        for (int j = 0; j < 4; ++j) {
            const int col = bn * 128 + wn * 64 + j * 16 + (lane & 15);
#pragma unroll
            for (int r2 = 0; r2 < 4; ++r2) {
                const int row = bm * 128 + wm * 64 + i * 16 + (lane >> 4) * 4 + r2;
                C[(size_t)row * N + col] = __float2bfloat16(acc[i][j][r2]);
            }
        }
    }
}

// --- fractional LIF scan: 3-LDS-episode tiles -------------------------------
// Mechanism being fixed: lgkmcnt is IN-ORDER per wave, so interleaving a
// hist ds_write and a (compiler-sunk) input ds_read every step serializes a
// full exposed LDS round-trip per step (~367 cyc/step measured). New tile
// structure has exactly 3 LDS episodes:
//   (1) batch all TB input reads, pinned by sched_barrier(0) (rule #18 —
//       otherwise the scheduler sinks them back to first use);
//   (2) pure-VALU sequential phase (dv buffered in registers);
//   (3) batch all TB hist writes at tile end (legal: in-tile scatter uses the
//       register copies; LDS hist is only read by FUTURE tiles' dense path;
//       lane columns are private).
// Inputs for BOTH scans staged in LDS up front via global_load_lds.
// Gates unchanged (bit-exact). Arithmetic expression/order identical.
template <bool FINAL>
__global__ __launch_bounds__(64) void flif_scan_kernel(const void* __restrict__ Iin,
                                                       void* __restrict__ spikes,
                                                       float* __restrict__ mems,
                                                       const float* __restrict__ ctab,
                                                       int NT, float kappa) {
    __shared__ float hist[T_STEPS * 64];        // [k][lane], 32 KB
    __shared__ __attribute__((aligned(16))) float cs[192];
    __shared__ __attribute__((aligned(16))) char inps[FINAL ? T_STEPS * 64 * 4 : T_STEPS * 64 * 2];
    const int lane = threadIdx.x;
    const int nid  = blockIdx.x * 64 + lane;

    if constexpr (!FINAL) {
        // bf16 input [128][64] = 16 KB; instr q covers rows q*8..q*8+7
#pragma unroll
        for (int q = 0; q < 16; ++q) {
            const __hip_bfloat16* g = (const __hip_bfloat16*)Iin +
                ((size_t)(q * 8 + (lane >> 3)) * NT + (size_t)blockIdx.x * 64 + (lane & 7) * 8);
            __builtin_amdgcn_global_load_lds((const __attribute__((address_space(1))) void*)g,
                                             (__attribute__((address_space(3))) void*)(inps + q * 1024),
                                             16, 0, 0);
        }
    } else {
        // f32 input [128][64] = 32 KB; instr q covers rows q*4..q*4+3
#pragma unroll
        for (int q = 0; q < 32; ++q) {
            const float* g = (const float*)Iin +
                ((size_t)(q * 4 + (lane >> 4)) * NT + (size_t)blockIdx.x * 64 + (lane & 15) * 4);
            __builtin_amdgcn_global_load_lds((const __attribute__((address_space(1))) void*)g,
                                             (__attribute__((address_space(3))) void*)(inps + q * 1024),
                                             16, 0, 0);
        }
    }

    for (int j = lane; j < 192; j += 64) cs[j] = ctab[j];
    __syncthreads();   // drains staging (vmcnt 0) + cs visible

    // c window for within-tile scatter (c[1..7]; index 0 unused)
    float cn_[TB];
#pragma unroll
    for (int j = 0; j < TB; ++j) cn_[j] = cs[j];

    float V = -70.f;
    unsigned dvbits = 0u;     // OR of all dv bit patterns produced so far

    for (int t = 0; t < T_STEPS / TB; ++t) {
        const int n0 = t * TB;

        // ---- episode 1: batch input reads (pinned early) ----
        float Ivv[TB];
#pragma unroll
        for (int i = 0; i < TB; ++i) {
            if constexpr (FINAL) Ivv[i] = ((const float*)inps)[(n0 + i) * 64 + lane];
            else                 Ivv[i] = __bfloat162float(((const __hip_bfloat16*)inps)[(n0 + i) * 64 + lane]);
        }
        __builtin_amdgcn_sched_barrier(0);

        float old_[TB];
#pragma unroll
        for (int i = 0; i < TB; ++i) old_[i] = 0.f;

        // ---- old-phase: skipped (bit-exactly) while history is all +0.0 ----
        if (__any(dvbits != 0u)) {
            for (int k0 = 0; k0 < n0; k0 += TB) {
                float hv[TB];
                unsigned sb = 0u;
#pragma unroll
                for (int kk = 0; kk < TB; ++kk) {
                    hv[kk] = hist[(k0 + kk) * 64 + lane];
                    sb |= __float_as_uint(hv[kk]);
                }
                if (__any(sb != 0u)) {
                    const int base = n0 - k0 - (TB - 1);   // >=1; base-1 multiple of 8
                    float cw[2 * TB];                      // cw[j] = c[base-1+j]
#pragma unroll
                    for (int q = 0; q < 4; ++q) {
                        const float4 cv = *reinterpret_cast<const float4*>(cs + (base - 1) + 4 * q);
                        cw[4 * q + 0] = cv.x; cw[4 * q + 1] = cv.y;
                        cw[4 * q + 2] = cv.z; cw[4 * q + 3] = cv.w;
                    }
#pragma unroll
                    for (int kk = 0; kk < TB; ++kk) {
#pragma unroll
                        for (int i = 0; i < TB; ++i)
                            old_[i] += hv[kk] * cw[TB - kk + i];
                    }
                }
            }
        }

        // ---- episode 2: sequential phase, pure VALU + global stores ----
        float dvb[TB];
#pragma unroll
        for (int i = 0; i < TB; ++i) {
            const int nm1 = n0 + i;                       // 0-based step index
            const float Iv = Ivv[i];
            const float f  = (-0.025f * (V + 70.f) + Iv) * 2.0f;   // /CM, CM=0.5
            const float Vn = kappa * f + V - old_[i];
            const bool  sp = (Vn >= -50.f);
            const float Vr = sp ? -70.f : Vn;
            const float dv = Vr - V;
            dvb[i] = dv;
            dvbits |= __float_as_uint(dv);
            // branchless scatter-forward (register copies; reference order)
#pragma unroll
            for (int i2 = i + 1; i2 < TB; ++i2)
                old_[i2] += dv * cn_[i2 - i];
            if (FINAL) {
                ((float*)spikes)[(size_t)nm1 * NT + nid] = sp ? 1.f : 0.f;
                mems[(size_t)nm1 * NT + nid] = Vr;
            } else {
                ((__hip_bfloat16*)spikes)[(size_t)nm1 * NT + nid] = __float2bfloat16(sp ? 1.f : 0.f);
            }
            V = Vr;
        }

        // ---- episode 3: batch hist writes ----
        __builtin_amdgcn_sched_barrier(0);
#pragma unroll
        for (int i = 0; i < TB; ++i)
            hist[(n0 + i) * 64 + lane] = dvb[i];
        __builtin_amdgcn_sched_barrier(0);
    }
}

// --- GEMM2: Io[r][o] = sum_h S[r][h]*Wo[o][h] -------------------------------
__global__ __launch_bounds__(256) void gemm2_kernel(const __hip_bfloat16* __restrict__ S,
                                                    const float* __restrict__ Wo,
                                                    float* __restrict__ Io) {
    const int wave = threadIdx.x >> 6, lane = threadIdx.x & 63;
    const int r0 = (blockIdx.x * 4 + wave) * 4;

    float wreg[NO][8];
#pragma unroll
    for (int o = 0; o < NO; ++o) {
        const float4 w0 = *reinterpret_cast<const float4*>(Wo + (size_t)o * NH + lane * 8);
        const float4 w1 = *reinterpret_cast<const float4*>(Wo + (size_t)o * NH + lane * 8 + 4);
        wreg[o][0] = w0.x; wreg[o][1] = w0.y; wreg[o][2] = w0.z; wreg[o][3] = w0.w;
        wreg[o][4] = w1.x; wreg[o][5] = w1.y; wreg[o][6] = w1.z; wreg[o][7] = w1.w;
    }

#pragma unroll
    for (int rr = 0; rr < 4; ++rr) {
        const int r = r0 + rr;
        u16x8 raw = *reinterpret_cast<const u16x8*>(S + (size_t)r * NH + lane * 8);
        float s[8];
#pragma unroll
        for (int j = 0; j < 8; ++j) s[j] = b2f_bits(raw[j]);
#pragma unroll
        for (int o = 0; o < NO; ++o) {
            float a = 0.f;
#pragma unroll
            for (int j = 0; j < 8; ++j) a += s[j] * wreg[o][j];
#pragma unroll
            for (int off = 32; off; off >>= 1) a += __shfl_xor(a, off);
            if (lane == o) Io[(size_t)r * NO + o] = a;
        }
    }
}

extern "C" void kernel_launch(void* const* d_in, const int* in_sizes, int n_in,
                              void* d_out, int out_size, void* d_ws, size_t ws_size,
                              hipStream_t stream) {
    const float* data = (const float*)d_in[0];   // [64][128][784]
    const float* Wh   = (const float*)d_in[1];   // [512][784]
    const float* Wo   = (const float*)d_in[2];   // [10][512]
    float* out = (float*)d_out;                  // f32! spikes then mems

    char* ws = (char*)d_ws;
    size_t off = 0;
    auto alloc = [&](size_t bytes) { void* p = ws + off; off += (bytes + 255) & ~255ull; return p; };
    __hip_bfloat16* Ab   = (__hip_bfloat16*)alloc((size_t)M1 * NIP * 2);  // 13.1 MB
    __hip_bfloat16* Whb  = (__hip_bfloat16*)alloc((size_t)NH * NIP * 2);  // 0.8 MB
    __hip_bfloat16* Ih   = (__hip_bfloat16*)alloc((size_t)M1 * NH * 2);   // 8.4 MB
    __hip_bfloat16* Sh   = (__hip_bfloat16*)alloc((size_t)M1 * NH * 2);   // 8.4 MB
    float*          Io   = (float*)alloc((size_t)M1 * NO * 4);            // 0.33 MB
    float*          ctab = (float*)alloc(192 * 4);

    const float kappa = (float)(std::pow(0.1, 0.2) * std::tgamma(1.8));

    prep_kernel<<<6801, 256, 0, stream>>>(data, Wh, Ab, Whb, ctab);

    dim3 g1(M1 / 128, NH / 128, 1);   // (64, 4)
    gemm_bf16_kernel<<<g1, 256, 0, stream>>>(Ab, Whb, Ih, NH, NIP);

    flif_scan_kernel<false><<<NT_H / 64, 64, 0, stream>>>(Ih, Sh, nullptr, ctab, NT_H, kappa);

    gemm2_kernel<<<M1 / 16, 256, 0, stream>>>(Sh, Wo, Io);

    flif_scan_kernel<true><<<NT_O / 64, 64, 0, stream>>>(Io, out, out + OUT_HALF, ctab, NT_O, kappa);
}